// Round 1
// baseline (472.604 us; speedup 1.0000x reference)
//
#include <hip/hip_runtime.h>
#include <hip/hip_bf16.h>
#include <math.h>

// LSMDecoder: out = sigmoid(bias - wg*N*dist_gam - wd*N*dist_del), plus zd/gd_raw/dd_raw.
// x[i,j] = bias - N*wg*a_i - N*wd*b_j - N * dot(A_i, B_j)  with 512-dim stacked A,B (fp16 MFMA).
// Diagonal overridden exactly (dist == 0 analytically). Off-diag x <= ~-12 -> sigmoid ~ 0,
// fp16 dot error (rms ~0.2 in x) is far below the 1.47e-2 output threshold.

#define NSZ 8192
#define DLAT 128

typedef _Float16 half8 __attribute__((ext_vector_type(8)));
typedef float f32x4 __attribute__((ext_vector_type(4)));

// ---------------- P1: column softmax of Wz/Wg/Wd (axis 0, 512 rows x 128 cols) -------------
__global__ void softmax_cols(const float* __restrict__ Wz, const float* __restrict__ Wg,
                             const float* __restrict__ Wd, float* __restrict__ T) {
    int col = blockIdx.x & 127;
    int m = blockIdx.x >> 7;
    const float* W = (m == 0) ? Wz : (m == 1 ? Wg : Wd);
    float* To = T + (size_t)m * 65536;
    int l = threadIdx.x;  // 64 threads = 1 wave
    float v[8];
    float mx = -3.4e38f;
    for (int i = 0; i < 8; ++i) {
        v[i] = W[(size_t)(i * 64 + l) * 128 + col];
        mx = fmaxf(mx, v[i]);
    }
    for (int off = 32; off; off >>= 1) mx = fmaxf(mx, __shfl_xor(mx, off));
    float s = 0.f;
    for (int i = 0; i < 8; ++i) { v[i] = expf(v[i] - mx); s += v[i]; }
    for (int off = 32; off; off >>= 1) s += __shfl_xor(s, off);
    float inv = 1.0f / s;
    for (int i = 0; i < 8; ++i) To[(size_t)(i * 64 + l) * 128 + col] = v[i] * inv;
}

// ---------------- P2: fp32 GEMM  [8192x512] @ [512x128] for zd / gd_raw / dd_raw -----------
// tile: 64 rows x 128 cols, K-chunks of 32. block 256 thr, micro-tile 4x8.
__global__ __launch_bounds__(256) void gemm3(const float* __restrict__ z,
                                             const float* __restrict__ gamma,
                                             const float* __restrict__ delta,
                                             const float* __restrict__ T,
                                             float* __restrict__ outTail) {
    int m = blockIdx.y;
    const float* A = (m == 0) ? z : (m == 1 ? gamma : delta);
    const float* B = T + (size_t)m * 65536;
    float* C = outTail + (size_t)m * (NSZ * DLAT);
    int rowBase = blockIdx.x * 64;
    __shared__ float As[32][68];    // transposed: As[k][row], +4 pad
    __shared__ float Bs[32][132];   // Bs[k][col], +4 pad
    int t = threadIdx.x;
    int cg = t & 15, rg = t >> 4;
    float acc[4][8] = {};
    for (int kt = 0; kt < 16; ++kt) {
        int k0 = kt * 32;
        for (int i = 0; i < 2; ++i) {            // stage A: 64 rows x 32 k
            int lin = i * 1024 + t * 4;
            int r = lin >> 5, kk = lin & 31;
            float4 va = *(const float4*)(A + (size_t)(rowBase + r) * 512 + k0 + kk);
            As[kk + 0][r] = va.x; As[kk + 1][r] = va.y;
            As[kk + 2][r] = va.z; As[kk + 3][r] = va.w;
        }
        for (int i = 0; i < 4; ++i) {            // stage B: 32 k x 128 cols
            int lin = i * 1024 + t * 4;
            int kk = lin >> 7, col = lin & 127;
            *(float4*)(&Bs[kk][col]) = *(const float4*)(B + (size_t)(k0 + kk) * 128 + col);
        }
        __syncthreads();
        for (int kk = 0; kk < 32; ++kk) {
            float a0[4], b0[8];
            *(float4*)a0 = *(const float4*)(&As[kk][rg * 4]);
            *(float4*)b0 = *(const float4*)(&Bs[kk][cg * 8]);
            *(float4*)(b0 + 4) = *(const float4*)(&Bs[kk][cg * 8 + 4]);
            for (int r = 0; r < 4; ++r)
                for (int c = 0; c < 8; ++c) acc[r][c] = fmaf(a0[r], b0[c], acc[r][c]);
        }
        __syncthreads();
    }
    for (int r = 0; r < 4; ++r) {
        int row = rowBase + rg * 4 + r;
        float4 s0 = make_float4(acc[r][0], acc[r][1], acc[r][2], acc[r][3]);
        float4 s1 = make_float4(acc[r][4], acc[r][5], acc[r][6], acc[r][7]);
        *(float4*)(C + (size_t)row * 128 + cg * 8) = s0;
        *(float4*)(C + (size_t)row * 128 + cg * 8 + 4) = s1;
    }
}

// ---------------- P2b: build fp16 stacked A/B [8192x512] + per-row scalars ------------------
__global__ void build_stacks(const float* __restrict__ zd, const float* __restrict__ gdr,
                             const float* __restrict__ ddr, _Float16* __restrict__ Afp,
                             _Float16* __restrict__ Bfp, float* __restrict__ cvec,
                             float* __restrict__ bco, const float* __restrict__ pb,
                             const float* __restrict__ pwg, const float* __restrict__ pwd) {
    int i = blockIdx.x;    // 8192 rows
    int k = threadIdx.x;   // 128
    float zv = zd[(size_t)i * 128 + k];
    float g = gdr[(size_t)i * 128 + k] + 1e-16f;
    float d = ddr[(size_t)i * 128 + k] + 1e-16f;
    float z2 = zv * zv;
    float u = 1.0f / g, p = 1.0f / d;
    float v = zv * u, q = zv * p;
    float wg = *pwg, wd = *pwd, bias = *pb;
    _Float16* Ar = Afp + (size_t)i * 512;
    _Float16* Br = Bfp + (size_t)i * 512;
    Ar[k]       = (_Float16)(wg * u);
    Ar[128 + k] = (_Float16)(wg * v);
    Ar[256 + k] = (_Float16)(wd * z2);
    Ar[384 + k] = (_Float16)(wd * zv);
    Br[k]       = (_Float16)(z2);
    Br[128 + k] = (_Float16)(-2.0f * zv);
    Br[256 + k] = (_Float16)(p);
    Br[384 + k] = (_Float16)(-2.0f * q);
    float a = z2 * u, b = z2 * p;
    for (int off = 32; off; off >>= 1) { a += __shfl_down(a, off); b += __shfl_down(b, off); }
    __shared__ float sa[2], sb[2];
    if ((k & 63) == 0) { sa[k >> 6] = a; sb[k >> 6] = b; }
    __syncthreads();
    if (k == 0) {
        cvec[i] = bias - 8192.0f * wg * (sa[0] + sa[1]);
        bco[i] = 8192.0f * wd * (sb[0] + sb[1]);
    }
}

// ---------------- P3: fp16 MFMA pair kernel, 128x128 tile, K=512, fused sigmoid -------------
__global__ __launch_bounds__(256) void pair_kernel(const _Float16* __restrict__ Afp,
                                                   const _Float16* __restrict__ Bfp,
                                                   const float* __restrict__ cvec,
                                                   const float* __restrict__ bco,
                                                   const float* __restrict__ pbias,
                                                   float* __restrict__ out) {
    // 8x8 supertile swizzle for L2 reuse
    int bid = blockIdx.x;
    int super = bid >> 6, within = bid & 63;
    int sy = super >> 3, sx = super & 7;
    int by = sy * 8 + (within >> 3), bx = sx * 8 + (within & 7);
    int iBase = by * 128, jBase = bx * 128;

    __shared__ _Float16 As[128 * 72];  // row stride 72 fp16 (144 B) -> uniform LDS banks
    __shared__ _Float16 Bs[128 * 72];
    int t = threadIdx.x;
    int l = t & 63, w = t >> 6;
    int wm = (w >> 1) * 64, wn = (w & 1) * 64;
    int lc = l & 15, lq = l >> 4;
    f32x4 acc[4][4] = {};

    for (int kt = 0; kt < 8; ++kt) {
        int k0 = kt * 64;
        for (int i = 0; i < 4; ++i) {     // stage 128 rows x 64 k per tile (16 KB each)
            int id = i * 256 + t;
            int row = id >> 3, pos = id & 7;
            *(uint4*)(&As[row * 72 + pos * 8]) =
                *(const uint4*)(Afp + (size_t)(iBase + row) * 512 + k0 + pos * 8);
            *(uint4*)(&Bs[row * 72 + pos * 8]) =
                *(const uint4*)(Bfp + (size_t)(jBase + row) * 512 + k0 + pos * 8);
        }
        __syncthreads();
        for (int ks = 0; ks < 2; ++ks) {
            half8 af[4], bf[4];
            for (int mi = 0; mi < 4; ++mi)
                af[mi] = *(const half8*)(&As[(wm + mi * 16 + lc) * 72 + ks * 32 + lq * 8]);
            for (int ni = 0; ni < 4; ++ni)
                bf[ni] = *(const half8*)(&Bs[(wn + ni * 16 + lc) * 72 + ks * 32 + lq * 8]);
            for (int mi = 0; mi < 4; ++mi)
                for (int ni = 0; ni < 4; ++ni)
                    acc[mi][ni] = __builtin_amdgcn_mfma_f32_16x16x32_f16(af[mi], bf[ni],
                                                                         acc[mi][ni], 0, 0, 0);
        }
        __syncthreads();
    }

    float bias = *pbias;
    float civ[4][4], bjv[4];
    for (int mi = 0; mi < 4; ++mi)
        for (int r = 0; r < 4; ++r)
            civ[mi][r] = cvec[iBase + wm + mi * 16 + lq * 4 + r];
    for (int ni = 0; ni < 4; ++ni) bjv[ni] = bco[jBase + wn + ni * 16 + lc];

    for (int mi = 0; mi < 4; ++mi) {
        for (int ni = 0; ni < 4; ++ni) {
            for (int r = 0; r < 4; ++r) {
                int i = iBase + wm + mi * 16 + lq * 4 + r;   // C/D: row = quad*4+reg
                int j = jBase + wn + ni * 16 + lc;           // C/D: col = lane&15
                float x = civ[mi][r] - bjv[ni] - 8192.0f * acc[mi][ni][r];
                if (i == j) x = bias;                        // exact diagonal (dist == 0)
                out[(size_t)i * NSZ + j] = 1.0f / (1.0f + expf(-x));
            }
        }
    }
}

extern "C" void kernel_launch(void* const* d_in, const int* in_sizes, int n_in,
                              void* d_out, int out_size, void* d_ws, size_t ws_size,
                              hipStream_t stream) {
    const float* z = (const float*)d_in[0];
    const float* gamma = (const float*)d_in[1];
    const float* delta = (const float*)d_in[2];
    const float* Wz = (const float*)d_in[3];
    const float* Wg = (const float*)d_in[4];
    const float* Wd = (const float*)d_in[5];
    const float* pb = (const float*)d_in[6];
    const float* pwg = (const float*)d_in[7];
    const float* pwd = (const float*)d_in[8];

    float* out = (float*)d_out;
    float* zd_out = out + (size_t)NSZ * NSZ;
    float* gd_out = zd_out + (size_t)NSZ * DLAT;
    float* dd_out = gd_out + (size_t)NSZ * DLAT;

    float* wsf = (float*)d_ws;
    float* T = wsf;                       // 3*512*128 f32 = 786 KB
    float* cvec = wsf + 196608;           // 8192
    float* bco = cvec + 8192;             // 8192
    _Float16* Afp = (_Float16*)(bco + 8192);          // 8192*512 fp16 = 8 MB
    _Float16* Bfp = Afp + (size_t)NSZ * 512;          // 8 MB

    softmax_cols<<<384, 64, 0, stream>>>(Wz, Wg, Wd, T);
    gemm3<<<dim3(128, 3), 256, 0, stream>>>(z, gamma, delta, T, zd_out);
    build_stacks<<<NSZ, 128, 0, stream>>>(zd_out, gd_out, dd_out, Afp, Bfp, cvec, bco,
                                          pb, pwg, pwd);
    pair_kernel<<<4096, 256, 0, stream>>>(Afp, Bfp, cvec, bco, pb, out);
}